// Round 6
// baseline (332.211 us; speedup 1.0000x reference)
//
#include <hip/hip_runtime.h>

// SpatialBottleneck — bf16 MFMA implicit-GEMM (NHWC), m97-style structure.
// Round 6: (a) revert conv1 fusion (round-5 regression: scattered 6 KB-stride
// staging loads + 1.5 blocks/CU latency-bound), back to gload16-from-Xh;
// (b) prep_x rewritten fully vectorized (float4 loads -> LDS 64x64 transpose,
// stride 65 -> 2-way=free -> uint4 bf16 stores); (c) double-buffered K-loop
// for conv1/conv2 (1 barrier/iter, loads in flight across compute phase).

#define BM 128
#define BNT 128
#define BK 64

typedef __attribute__((ext_vector_type(8))) short short8;
typedef __attribute__((ext_vector_type(4))) float f32x4;

__device__ inline unsigned short f2bf(float f) {
    unsigned int u = __float_as_uint(f);
    u += 0x7fff + ((u >> 16) & 1);            // RNE
    return (unsigned short)(u >> 16);
}

__device__ inline void gload16(const unsigned short* g, unsigned short* l) {
    __builtin_amdgcn_global_load_lds(
        (const __attribute__((address_space(1))) unsigned int*)g,
        (__attribute__((address_space(3))) unsigned int*)l, 16, 0, 0);
}

// ---------------- prep: x NCHW fp32 -> NHWC bf16 (vectorized both sides) ----------------
__global__ __launch_bounds__(256) void prep_x(const float* __restrict__ x,
                                              unsigned short* __restrict__ Xh) {
    __shared__ float t[64 * 65];
    const int p0 = blockIdx.x * 64, c0 = blockIdx.y * 64, n = blockIdx.z;
    const int tid = threadIdx.x;
    // phase 1: coalesced float4 loads along px; rows = channels
    {
        const int px4 = (tid & 15) * 4;
        const int r0 = tid >> 4;                  // 0..15
        const float* xb = x + ((size_t)n * 1024 + c0 + r0) * 784 + p0 + px4;
        #pragma unroll
        for (int j = 0; j < 4; ++j) {
            int row = r0 + j * 16;
            float4 v = make_float4(0.f, 0.f, 0.f, 0.f);
            if (p0 + px4 + 3 < 784) v = *(const float4*)(xb + (size_t)j * 16 * 784);
            t[row * 65 + px4 + 0] = v.x;
            t[row * 65 + px4 + 1] = v.y;
            t[row * 65 + px4 + 2] = v.z;
            t[row * 65 + px4 + 3] = v.w;
        }
    }
    __syncthreads();
    // phase 2: read 8 ch per thread (2-way bank alias = free), pack, uint4 store
    {
        const int cg = tid & 7;                   // 16B chunk within 64-ch tile
        #pragma unroll
        for (int r2 = 0; r2 < 2; ++r2) {
            int px = (tid >> 3) + 32 * r2;        // 0..63
            if (p0 + px < 784) {
                unsigned pk[4];
                #pragma unroll
                for (int j = 0; j < 4; ++j) {
                    float f0 = t[(cg * 8 + 2 * j) * 65 + px];
                    float f1 = t[(cg * 8 + 2 * j + 1) * 65 + px];
                    pk[j] = (unsigned)f2bf(f0) | ((unsigned)f2bf(f1) << 16);
                }
                *(uint4*)(Xh + (size_t)(n * 784 + p0 + px) * 1024 + c0 + cg * 8) =
                    make_uint4(pk[0], pk[1], pk[2], pk[3]);
            }
        }
    }
}

// ---------------- prep: weights -> bf16, w2 -> [tap][co][ci]; BN fold ----------------
__global__ __launch_bounds__(256) void prep_w(
    const float* __restrict__ w1, const float* __restrict__ w2, const float* __restrict__ w3,
    const float* g1, const float* b1, const float* m1, const float* v1,
    const float* g2, const float* b2, const float* m2, const float* v2,
    const float* g3, const float* b3, const float* m3, const float* v3,
    unsigned short* __restrict__ Wb1, unsigned short* __restrict__ Wt2,
    unsigned short* __restrict__ Wb3,
    float* __restrict__ bn1, float* __restrict__ bn2, float* __restrict__ bn3) {
    int i = blockIdx.x * 256 + threadIdx.x;
    if (i < 262144) Wb1[i] = f2bf(w1[i]);
    if (i < 589824) {
        int kw = i % 3, t1 = i / 3;
        int kh = t1 % 3, t2 = t1 / 3;
        int ci = t2 & 255, co = t2 >> 8;
        Wt2[(size_t)((kh * 3 + kw) * 256 + co) * 256 + ci] = f2bf(w2[i]);
    }
    if (i < 262144) Wb3[i] = f2bf(w3[i]);
    if (i < 256) { float s = g1[i] * rsqrtf(v1[i]); bn1[i] = s; bn1[256 + i] = b1[i] - m1[i] * s; }
    if (i < 256) { float s = g2[i] * rsqrtf(v2[i]); bn2[i] = s; bn2[256 + i] = b2[i] - m2[i] * s; }
    if (i < 1024) { float s = g3[i] * rsqrtf(v3[i]); bn3[i] = s; bn3[1024 + i] = b3[i] - m3[i] * s; }
}

// Zero only the 116 border cells per image of y1p [32][900][256] (conv1 fills interior).
__global__ __launch_bounds__(256) void border_zero(uint4* __restrict__ y1p) {
    int i = blockIdx.x * 256 + threadIdx.x;      // 464*256 = 118784 = 32*116*32
    int ch8 = i & 31;
    int t = i >> 5;
    int cell = t % 116;
    int n = t / 116;
    int h, w;
    if (cell < 30)      { h = 0;          w = cell; }
    else if (cell < 60) { h = 29;         w = cell - 30; }
    else if (cell < 88) { h = cell - 59;  w = 0; }
    else                { h = cell - 87;  w = 29; }
    y1p[((size_t)n * 900 + h * 30 + w) * 32 + ch8] = make_uint4(0u, 0u, 0u, 0u);
}

// ---------------- MFMA implicit-GEMM conv body ----------------
// LAYER 1: y1p padded NHWC bf16; LAYER 2: y2 NHWC bf16; LAYER 3: fp32 NCHW + resid
template <int CX, int NTAPS, int LAYER, int DBUF>
__device__ __forceinline__ void conv_body(
    const unsigned short* __restrict__ Xg, const unsigned short* __restrict__ Wg,
    const float* __restrict__ bn, int nco,
    const float* __restrict__ residual,
    unsigned short* __restrict__ obf, float* __restrict__ ofp) {
    constexpr int KITER = CX / BK;
    constexpr int NIT = NTAPS * KITER;
    __shared__ __align__(16) char smem[DBUF ? 65536 : (LAYER == 3 ? 33792 : 32768)];
    const int tid = threadIdx.x;
    const int wave = tid >> 6, lane = tid & 63;
    const int quad = lane >> 4, l15 = lane & 15;
    const int Pb = blockIdx.x * BM;
    const int cb = blockIdx.y * BNT;
    const int wco = (wave & 1) * 64;
    const int wpx = (wave >> 1) * 64;

    // staging precompute: 4 rounds, slot = t*256 + tid -> (row, phys chunk)
    int rowt[4], cso[4];
    size_t xrow[4];
    #pragma unroll
    for (int t = 0; t < 4; ++t) {
        int slot = t * 256 + tid;
        int row = slot >> 3;
        int c = slot & 7;
        rowt[t] = row;
        cso[t] = ((c ^ (row & 7)) * 8);           // element offset of global chunk
        if (LAYER == 2) {
            int P = Pb + row;
            int n = P / 784, rem = P - n * 784;
            int h = rem / 28, w = rem - h * 28;
            xrow[t] = (size_t)n * 900 + h * 30 + w;   // padded-row base (tap adds kh*30+kw)
        } else {
            xrow[t] = (size_t)(Pb + row);
        }
    }

    f32x4 acc[4][4];
    #pragma unroll
    for (int i = 0; i < 4; ++i)
        #pragma unroll
        for (int j = 0; j < 4; ++j)
            acc[i][j] = (f32x4){0.f, 0.f, 0.f, 0.f};

    auto stage = [&](int it, int b) {
        unsigned short* Xs = (unsigned short*)(smem + b * 32768);
        unsigned short* Ws = (unsigned short*)(smem + b * 32768 + 16384);
        const int tap = (NTAPS == 1) ? 0 : it / KITER;
        const int k0 = (it % KITER) * BK;
        const int tapofs = (NTAPS == 9) ? ((tap / 3) * 30 + (tap % 3)) : 0;
        const unsigned short* Wtap = Wg + (size_t)tap * 256 * CX;
        #pragma unroll
        for (int t = 0; t < 4; ++t)
            gload16(Wtap + (size_t)(cb + rowt[t]) * CX + k0 + cso[t],
                    Ws + (size_t)(t * 256 + wave * 64) * 8);
        #pragma unroll
        for (int t = 0; t < 4; ++t)
            gload16(Xg + (xrow[t] + tapofs) * (size_t)CX + k0 + cso[t],
                    Xs + (size_t)(t * 256 + wave * 64) * 8);
    };
    auto compute = [&](int b) {
        unsigned short* Xs = (unsigned short*)(smem + b * 32768);
        unsigned short* Ws = (unsigned short*)(smem + b * 32768 + 16384);
        #pragma unroll
        for (int kk = 0; kk < BK; kk += 32) {
            short8 af[4], bf[4];
            const int cbase = kk >> 3;                // 0 or 4
            #pragma unroll
            for (int wi = 0; wi < 4; ++wi) {
                int row = wco + wi * 16 + l15;
                int ch = (cbase + quad) ^ (row & 7);
                af[wi] = *(const short8*)(Ws + (row * 8 + ch) * 8);
            }
            #pragma unroll
            for (int wj = 0; wj < 4; ++wj) {
                int row = wpx + wj * 16 + l15;
                int ch = (cbase + quad) ^ (row & 7);
                bf[wj] = *(const short8*)(Xs + (row * 8 + ch) * 8);
            }
            #pragma unroll
            for (int wi = 0; wi < 4; ++wi)
                #pragma unroll
                for (int wj = 0; wj < 4; ++wj)
                    acc[wi][wj] = __builtin_amdgcn_mfma_f32_16x16x32_bf16(
                        af[wi], bf[wj], acc[wi][wj], 0, 0, 0);
        }
    };

    if (DBUF) {
        stage(0, 0);
        for (int it = 0; it < NIT; ++it) {
            __syncthreads();                      // drains this wave's vmcnt -> buf(it) ready
            if (it + 1 < NIT) stage(it + 1, (it + 1) & 1);
            compute(it & 1);                      // overlaps with in-flight stage(it+1)
        }
    } else {
        for (int it = 0; it < NIT; ++it) {
            __syncthreads();
            stage(it, 0);
            __syncthreads();
            compute(0);
        }
    }

    __syncthreads();   // protect smem reuse: all frag reads done before epilogue writes

    if (LAYER == 3) {
        // fp32 NCHW + residual + ReLU, two co-half passes through LDS [64][132] f32
        float* ep = (float*)smem;
        #pragma unroll
        for (int pass = 0; pass < 2; ++pass) {
            if ((wave & 1) == pass) {
                #pragma unroll
                for (int wi = 0; wi < 4; ++wi) {
                    int co0 = cb + wco + wi * 16 + quad * 4;
                    f32x4 sc = *(const f32x4*)(bn + co0);
                    f32x4 bi = *(const f32x4*)(bn + nco + co0);
                    int cr0 = wi * 16 + quad * 4;          // 0..63 local co row
                    #pragma unroll
                    for (int wj = 0; wj < 4; ++wj) {
                        int px = wpx + wj * 16 + l15;      // 0..127
                        #pragma unroll
                        for (int r = 0; r < 4; ++r)
                            ep[(cr0 + r) * 132 + px] = fmaf(acc[wi][wj][r], sc[r], bi[r]);
                    }
                }
            }
            __syncthreads();
            {
                int cr = tid >> 2;                         // 0..63
                int cg = tid & 3;
                int co = cb + pass * 64 + cr;
                #pragma unroll
                for (int k = 0; k < 8; ++k) {
                    int px4 = (cg + 4 * k) * 4;            // 0..124
                    f32x4 v = *(const f32x4*)(ep + cr * 132 + px4);
                    int P = Pb + px4;
                    int n = P / 784, p = P - n * 784;
                    size_t off = ((size_t)n * 1024 + co) * 784 + p;
                    float4 rs = *(const float4*)(residual + off);
                    float4 o;
                    o.x = v[0] + rs.x; o.x = o.x > 0.f ? o.x : 0.f;
                    o.y = v[1] + rs.y; o.y = o.y > 0.f ? o.y : 0.f;
                    o.z = v[2] + rs.z; o.z = o.z > 0.f ? o.z : 0.f;
                    o.w = v[3] + rs.w; o.w = o.w > 0.f ? o.w : 0.f;
                    *(float4*)(ofp + off) = o;
                }
            }
            __syncthreads();
        }
    } else {
        // bf16 NHWC (+BN+ReLU), two px-half passes through LDS [64][136] ushort
        unsigned short* ep = (unsigned short*)smem;
        #pragma unroll
        for (int pass = 0; pass < 2; ++pass) {
            if ((wave >> 1) == pass) {
                #pragma unroll
                for (int wi = 0; wi < 4; ++wi) {
                    int co0 = cb + wco + wi * 16 + quad * 4;
                    f32x4 sc = *(const f32x4*)(bn + co0);
                    f32x4 bi = *(const f32x4*)(bn + nco + co0);
                    int col = wco + wi * 16 + quad * 4;    // 0..127 local co
                    #pragma unroll
                    for (int wj = 0; wj < 4; ++wj) {
                        int pxl = wj * 16 + l15;           // 0..63 within pass
                        float v0 = fmaf(acc[wi][wj][0], sc[0], bi[0]); v0 = v0 > 0.f ? v0 : 0.f;
                        float v1 = fmaf(acc[wi][wj][1], sc[1], bi[1]); v1 = v1 > 0.f ? v1 : 0.f;
                        float v2 = fmaf(acc[wi][wj][2], sc[2], bi[2]); v2 = v2 > 0.f ? v2 : 0.f;
                        float v3 = fmaf(acc[wi][wj][3], sc[3], bi[3]); v3 = v3 > 0.f ? v3 : 0.f;
                        uint2 pk;
                        pk.x = (unsigned)f2bf(v0) | ((unsigned)f2bf(v1) << 16);
                        pk.y = (unsigned)f2bf(v2) | ((unsigned)f2bf(v3) << 16);
                        *(uint2*)(ep + pxl * 136 + col) = pk;
                    }
                }
            }
            __syncthreads();
            {
                int pxl = tid >> 2;                        // 0..63
                int cg = tid & 3;
                int P = Pb + pass * 64 + pxl;
                size_t orow;
                if (LAYER == 1) {
                    int n = P / 784, rem = P - n * 784;
                    int h = rem / 28, w = rem - h * 28;
                    orow = (size_t)n * 900 + (h + 1) * 30 + (w + 1);
                } else {
                    orow = (size_t)P;
                }
                #pragma unroll
                for (int k = 0; k < 4; ++k) {
                    int cc = (cg + 4 * k) * 8;             // ushort offset 0..120
                    uint4 v = *(const uint4*)(ep + pxl * 136 + cc);
                    *(uint4*)(obf + orow * 256 + cb + cc) = v;
                }
            }
            __syncthreads();
        }
    }
}

__global__ __launch_bounds__(256) void conv1_mfma(
    const unsigned short* __restrict__ Xg, const unsigned short* __restrict__ Wg,
    const float* __restrict__ bn, unsigned short* __restrict__ obf) {
    conv_body<1024, 1, 1, 1>(Xg, Wg, bn, 256, nullptr, obf, nullptr);
}
__global__ __launch_bounds__(256) void conv2_mfma(
    const unsigned short* __restrict__ Xg, const unsigned short* __restrict__ Wg,
    const float* __restrict__ bn, unsigned short* __restrict__ obf) {
    conv_body<256, 9, 2, 1>(Xg, Wg, bn, 256, nullptr, obf, nullptr);
}
__global__ __launch_bounds__(256) void conv3_mfma(
    const unsigned short* __restrict__ Xg, const unsigned short* __restrict__ Wg,
    const float* __restrict__ bn, const float* __restrict__ residual,
    float* __restrict__ ofp) {
    conv_body<256, 1, 3, 0>(Xg, Wg, bn, 1024, residual, nullptr, ofp);
}

extern "C" void kernel_launch(void* const* d_in, const int* in_sizes, int n_in,
                              void* d_out, int out_size, void* d_ws, size_t ws_size,
                              hipStream_t stream) {
    const float* x  = (const float*)d_in[0];
    const float* w1 = (const float*)d_in[1];
    const float* w2 = (const float*)d_in[2];
    const float* w3 = (const float*)d_in[3];
    const float* g1 = (const float*)d_in[4];  const float* b1 = (const float*)d_in[5];
    const float* m1 = (const float*)d_in[6];  const float* v1 = (const float*)d_in[7];
    const float* g2 = (const float*)d_in[8];  const float* b2 = (const float*)d_in[9];
    const float* m2 = (const float*)d_in[10]; const float* v2 = (const float*)d_in[11];
    const float* g3 = (const float*)d_in[12]; const float* b3 = (const float*)d_in[13];
    const float* m3 = (const float*)d_in[14]; const float* v3 = (const float*)d_in[15];
    float* out = (float*)d_out;

    char* ws = (char*)d_ws;
    unsigned short* Xh  = (unsigned short*)(ws);                    // 25088*1024*2 = 51,380,224
    unsigned short* y1p = (unsigned short*)(ws + 51380224);         // 32*900*256*2 = 14,745,600
    unsigned short* y2  = (unsigned short*)(ws + 66125824);         // 25088*256*2  = 12,845,056
    unsigned short* Wb1 = (unsigned short*)(ws + 78970880);         // 524,288
    unsigned short* Wt2 = (unsigned short*)(ws + 79495168);         // 1,179,648
    unsigned short* Wb3 = (unsigned short*)(ws + 80674816);         // 524,288
    float* bn1 = (float*)(ws + 81199104);                           // 2 KB
    float* bn2 = (float*)(ws + 81201152);                           // 2 KB
    float* bn3 = (float*)(ws + 81203200);                           // 8 KB

    prep_x<<<dim3(13, 16, 32), 256, 0, stream>>>(x, Xh);
    prep_w<<<2304, 256, 0, stream>>>(w1, w2, w3,
                                     g1, b1, m1, v1, g2, b2, m2, v2, g3, b3, m3, v3,
                                     Wb1, Wt2, Wb3, bn1, bn2, bn3);
    border_zero<<<464, 256, 0, stream>>>((uint4*)y1p);

    conv1_mfma<<<dim3(196, 2), 256, 0, stream>>>(Xh, Wb1, bn1, y1p);
    conv2_mfma<<<dim3(196, 2), 256, 0, stream>>>(y1p, Wt2, bn2, y2);
    conv3_mfma<<<dim3(196, 8), 256, 0, stream>>>(y2, Wb3, bn3, x, out);
}